// Round 18
// baseline (112.919 us; speedup 1.0000x reference)
//
#include <hip/hip_runtime.h>
#include <hip/hip_bf16.h>

typedef __attribute__((ext_vector_type(8))) short bf16x8;
typedef __attribute__((ext_vector_type(4))) float f32x4;
typedef __attribute__((ext_vector_type(4))) unsigned short u16x4;
typedef unsigned short u16;

#define M_DIM 50176
#define N_DIM 768
#define K_DIM 768
#define NTILES 2352      // (M/128)*(N/128)
#define GRID 512         // persistent: exactly 2 blocks/CU

__device__ __forceinline__ u16 f2bf(float f) {
    __hip_bfloat16 h = __float2bfloat16(f);
    return *reinterpret_cast<u16*>(&h);
}

__device__ __forceinline__ void gld_lds16(const void* g, void* l) {
    __builtin_amdgcn_global_load_lds(
        (const __attribute__((address_space(1))) unsigned int*)g,
        (__attribute__((address_space(3))) unsigned int*)l, 16, 0, 0);
}

// ---------------- Kernel 1: fold weights ----------------
__global__ void fold_weights(const float* __restrict__ qkv_w,
                             const float* __restrict__ qkv_b,
                             const float* __restrict__ proj_w,
                             const float* __restrict__ proj_b,
                             const float* __restrict__ pe,
                             u16* __restrict__ Bw, float* __restrict__ bias) {
    const int o = blockIdx.x;
    const int t = threadIdx.x;
    __shared__ float wv[16];
    __shared__ float bv4[4];
    __shared__ float red[4];
    if (t < 16) wv[t] = qkv_w[32 + t];
    if (t < 4)  bv4[t] = qkv_b[8 + t];
    __syncthreads();
    const float* Prow = proj_w + o * 768;
    float s = 0.f;
    for (int c = t; c < 768; c += 256) {
        int g4 = c & ~3, j = c & 3;
        float af = Prow[g4 + 0] * wv[0 * 4 + j] + Prow[g4 + 1] * wv[1 * 4 + j] +
                   Prow[g4 + 2] * wv[2 * 4 + j] + Prow[g4 + 3] * wv[3 * 4 + j];
        Bw[o * 768 + c] = f2bf(af);
        s += af * pe[c];
        s += Prow[c] * bv4[j];
    }
    #pragma unroll
    for (int off = 32; off; off >>= 1) s += __shfl_down(s, off, 64);
    if ((t & 63) == 0) red[t >> 6] = s;
    __syncthreads();
    if (t == 0) bias[o] = red[0] + red[1] + red[2] + red[3] + proj_b[o];
}

// ---------------- Kernel 2: persistent fused GEMM (R12 core + tile prefetch) --
// Y[m,o] = sum_c bf16(X[m,c]) * Bw[o,c] + bias[o]
// R12 K-loop byte-for-byte (128x128 tile, BK=64, 4 waves 2x2, dbuf swizzled
// LDS A+B, depth-2 A-reg pipeline, setprio around MFMA, NT dense epilogue).
// Persistent: 512 blocks, block p does tiles p, p+512, ... Between tiles the
// next tile's prologue loads (preA, preB, gld_lds B0) are issued BEFORE the
// epilogue (Bs[0]/preA/preB provably dead at K-loop exit) and drained for
// free at the post-epilogue barrier -> exposed prologue eliminated.
// Epilogue restricted to the first 32 KiB (As region; Bs[0] has in-flight
// gld_lds writes): two 64-row passes.
__global__ __launch_bounds__(256, 2)
void gemm_fused(const float* __restrict__ X, const u16* __restrict__ Bw,
                const float* __restrict__ bias, float* __restrict__ Y) {
    const int tid = threadIdx.x;
    const int lane = tid & 63;
    const int w = tid >> 6;
    const int wm = w >> 1, wn = w & 1;

    // 64 KB: As[2] (0..32K) | Bs[2] (32..64K). Epilogue pool = first 32 KB.
    __shared__ __align__(16) float pool[16384];
    u16 (*As)[128 * 64] = (u16(*)[128 * 64])pool;
    u16 (*Bs)[128 * 64] = (u16(*)[128 * 64])((char*)pool + 32768);

    f32x4 acc[4][4];

    const int arow = tid >> 4;      // 0..15
    const int agg  = tid & 15;      // 16B fp32 granule within row
    const int bg = lane & 7;

    float4 preA[8], preB[8];

    auto load_a = [&](float4 (&p)[8], const float* xbase, int k0) {
        const float4* src = (const float4*)(xbase + k0);
        #pragma unroll
        for (int i = 0; i < 8; ++i) {
            int r = arow + 16 * i;
            p[i] = src[(long)r * (K_DIM / 4) + agg];
        }
    };

    auto write_a = [&](int buf, const float4 (&p)[8]) {
        #pragma unroll
        for (int i = 0; i < 8; ++i) {
            int r = arow + 16 * i;
            int pb = (agg * 8) ^ ((r & 7) << 4);   // bf16 byte offset in row
            u16x4 hv;
            hv.x = f2bf(p[i].x);
            hv.y = f2bf(p[i].y);
            hv.z = f2bf(p[i].z);
            hv.w = f2bf(p[i].w);
            *(u16x4*)&As[buf][r * 64 + (pb >> 1)] = hv;
        }
    };

    auto stage_b = [&](int buf, const u16* bwbase, int k0) {
        #pragma unroll
        for (int j = 0; j < 4; ++j) {
            int rowbase = j * 32 + w * 8;
            int row = rowbase + (lane >> 3);
            // pre-swizzled global source, linear LDS dest (base + lane*16)
            const char* src = (const char*)bwbase + ((long)row * K_DIM + k0) * 2 +
                              ((bg * 16) ^ ((row & 7) << 4));
            gld_lds16(src, (void*)&Bs[buf][rowbase * 64]);
        }
    };

    auto compute = [&](int buf) {
        #pragma unroll
        for (int h = 0; h < 2; ++h) {
            bf16x8 av[4], bv_[4];
            #pragma unroll
            for (int mf = 0; mf < 4; ++mf) {
                int r = wm * 64 + mf * 16 + (lane & 15);
                int pb = (h * 64 + ((lane >> 4) << 4)) ^ ((r & 7) << 4);
                av[mf] = *(const bf16x8*)&As[buf][r * 64 + (pb >> 1)];
            }
            #pragma unroll
            for (int nf = 0; nf < 4; ++nf) {
                int r = wn * 64 + nf * 16 + (lane & 15);
                int pb = (h * 64 + ((lane >> 4) << 4)) ^ ((r & 7) << 4);
                bv_[nf] = *(const bf16x8*)&Bs[buf][r * 64 + (pb >> 1)];
            }
            __builtin_amdgcn_s_setprio(1);
            #pragma unroll
            for (int mf = 0; mf < 4; ++mf)
                #pragma unroll
                for (int nf = 0; nf < 4; ++nf)
                    acc[mf][nf] = __builtin_amdgcn_mfma_f32_16x16x32_bf16(
                        av[mf], bv_[nf], acc[mf][nf], 0, 0, 0);
            __builtin_amdgcn_s_setprio(0);
        }
    };

    // tile index -> coordinates (XCD-aware bijective swizzle: 2352 = 8*294)
    auto tilecoords = [&](int t, long& m0_, int& n0_) {
        int bid = (t & 7) * 294 + (t >> 3);
        int mt = bid / 6, nt = bid - mt * 6;
        m0_ = (long)mt * 128;
        n0_ = nt * 128;
    };

    int tile = blockIdx.x;
    long m0; int n0;
    tilecoords(tile, m0, n0);
    const float* xb = X + m0 * K_DIM;
    const u16*   bb = Bw + (long)n0 * K_DIM;

    // ---- first-tile prologue ----
    load_a(preA, xb, 0);
    stage_b(0, bb, 0);
    load_a(preB, xb, 64);
    write_a(0, preA);          // waits only preA; preB + gld_lds stay in flight
    __syncthreads();

    #pragma unroll 1
    for (;;) {
        #pragma unroll
        for (int i = 0; i < 4; ++i)
            #pragma unroll
            for (int j = 0; j < 4; ++j)
                acc[i][j] = (f32x4){0.f, 0.f, 0.f, 0.f};

        // ---- K-loop: R12 verbatim ----
        const int NT = K_DIM / 64;  // 12
        #pragma unroll 1
        for (int t2 = 0; t2 < NT; t2 += 2) {
            if (t2 + 1 < NT) {
                write_a(1, preB);                  // A for t+1
                stage_b(1, bb, (t2 + 1) * 64);     // B for t+1
            }
            if (t2 + 2 < NT) load_a(preA, xb, (t2 + 2) * 64);
            compute(0);
            __syncthreads();

            if (t2 + 2 < NT) {
                write_a(0, preA);
                stage_b(0, bb, (t2 + 2) * 64);
            }
            if (t2 + 3 < NT) load_a(preB, xb, (t2 + 3) * 64);
            compute(1);
            __syncthreads();
        }
        // K-loop exit: As/Bs dead; preA/preB dead.

        // ---- next-tile prefetch (flies during the epilogue) ----
        int ntile = tile + GRID;
        bool has_next = ntile < NTILES;
        long nm0 = 0; int nn0 = 0;
        const float* nxb = nullptr; const u16* nbb = nullptr;
        if (has_next) {
            tilecoords(ntile, nm0, nn0);
            nxb = X + nm0 * K_DIM;
            nbb = Bw + (long)nn0 * K_DIM;
            load_a(preA, nxb, 0);       // -> regs, written to As[0] post-epilogue
            load_a(preB, nxb, 64);
            stage_b(0, nbb, 0);         // async into Bs[0] (untouched below)
        }

        // ---- epilogue: two 64-row passes via pool = first 32 KiB ----
        // C/D layout col=lane&15, row=(lane>>4)*4+reg; wave wm owns rows wm*64..+63.
        const int colq = lane & 15;
        const int rowq = (lane >> 4) * 4;
        #pragma unroll
        for (int p = 0; p < 2; ++p) {
            if (wm == p) {
                #pragma unroll
                for (int nf = 0; nf < 4; ++nf) {
                    int col = wn * 64 + nf * 16 + colq;
                    float bi = bias[n0 + col];
                    #pragma unroll
                    for (int mf = 0; mf < 4; ++mf) {
                        #pragma unroll
                        for (int r = 0; r < 4; ++r) {
                            int rl = mf * 16 + rowq + r;               // 0..63
                            int colS = col ^ (((rl >> 2) & 1) << 4);   // 2-way max
                            pool[rl * 128 + colS] = acc[mf][nf][r] + bi;
                        }
                    }
                }
            }
            __syncthreads();
            #pragma unroll
            for (int i = 0; i < 8; ++i) {
                int chunk = i * 256 + tid;     // 0..2047
                int rl = chunk >> 5;           // 0..63
                int g = chunk & 31;            // float4 granule in row
                int gs = g ^ (((rl >> 2) & 1) << 2);
                f32x4 v = *(const f32x4*)&pool[rl * 128 + gs * 4];
                __builtin_nontemporal_store(v,
                    (f32x4*)&Y[(m0 + p * 64 + rl) * N_DIM + n0 + g * 4]);
            }
            __syncthreads();
        }

        if (!has_next) return;

        // ---- establish next tile's K-loop entry invariant ----
        write_a(0, preA);      // drain is ~free: loads flew during epilogue
        __syncthreads();       // As[0] visible + Bs[0] gld_lds drained
        tile = ntile; m0 = nm0; n0 = nn0; xb = nxb; bb = nbb;
    }
}

extern "C" void kernel_launch(void* const* d_in, const int* in_sizes, int n_in,
                              void* d_out, int out_size, void* d_ws, size_t ws_size,
                              hipStream_t stream) {
    const float* x      = (const float*)d_in[0];
    const float* qkv_w  = (const float*)d_in[1];
    const float* qkv_b  = (const float*)d_in[2];
    const float* proj_w = (const float*)d_in[3];
    const float* proj_b = (const float*)d_in[4];
    const float* pe     = (const float*)d_in[5];
    float* y = (float*)d_out;

    u16*   Bw   = (u16*)d_ws;
    float* bias = (float*)((char*)d_ws + (size_t)N_DIM * K_DIM * 2);

    fold_weights<<<768, 256, 0, stream>>>(qkv_w, qkv_b, proj_w, proj_b, pe, Bw, bias);
    gemm_fused<<<GRID, 256, 0, stream>>>(x, Bw, bias, y);
}

// Round 19
// 100.214 us; speedup vs baseline: 1.1268x; 1.1268x over previous
//
#include <hip/hip_runtime.h>
#include <hip/hip_bf16.h>

typedef __attribute__((ext_vector_type(8))) short bf16x8;
typedef __attribute__((ext_vector_type(4))) float f32x4;
typedef __attribute__((ext_vector_type(4))) unsigned short u16x4;
typedef unsigned short u16;

#define M_DIM 50176
#define N_DIM 768
#define K_DIM 768

__device__ __forceinline__ u16 f2bf(float f) {
    __hip_bfloat16 h = __float2bfloat16(f);
    return *reinterpret_cast<u16*>(&h);
}

__device__ __forceinline__ void gld_lds16(const void* g, void* l) {
    __builtin_amdgcn_global_load_lds(
        (const __attribute__((address_space(1))) unsigned int*)g,
        (__attribute__((address_space(3))) unsigned int*)l, 16, 0, 0);
}

// ---------------- Kernel 1: fold weights ----------------
// The op collapses: softmax over a single key == 1, so out == v. Folding the
// block-diagonal v-projection into proj gives Y = X @ A'^T + b'' — one GEMM
// with weight A' (768x768, bf16) and bias b'' computed here once per call.
__global__ void fold_weights(const float* __restrict__ qkv_w,
                             const float* __restrict__ qkv_b,
                             const float* __restrict__ proj_w,
                             const float* __restrict__ proj_b,
                             const float* __restrict__ pe,
                             u16* __restrict__ Bw, float* __restrict__ bias) {
    const int o = blockIdx.x;
    const int t = threadIdx.x;
    __shared__ float wv[16];
    __shared__ float bv4[4];
    __shared__ float red[4];
    if (t < 16) wv[t] = qkv_w[32 + t];
    if (t < 4)  bv4[t] = qkv_b[8 + t];
    __syncthreads();
    const float* Prow = proj_w + o * 768;
    float s = 0.f;
    for (int c = t; c < 768; c += 256) {
        int g4 = c & ~3, j = c & 3;
        float af = Prow[g4 + 0] * wv[0 * 4 + j] + Prow[g4 + 1] * wv[1 * 4 + j] +
                   Prow[g4 + 2] * wv[2 * 4 + j] + Prow[g4 + 3] * wv[3 * 4 + j];
        Bw[o * 768 + c] = f2bf(af);
        s += af * pe[c];
        s += Prow[c] * bv4[j];
    }
    #pragma unroll
    for (int off = 32; off; off >>= 1) s += __shfl_down(s, off, 64);
    if ((t & 63) == 0) red[t >> 6] = s;
    __syncthreads();
    if (t == 0) bias[o] = red[0] + red[1] + red[2] + red[3] + proj_b[o];
}

// ---------------- Kernel 2: fused GEMM (champion, R12 verbatim) -------------
// Y[m,o] = sum_c bf16(X[m,c]) * Bw[o,c] + bias[o]
// 128x128 tile, BK=64, 4 waves (2x2), double-buffered swizzled LDS for A and
// B, depth-2 A-reg pipeline, issue-early/write-late, setprio(1) around MFMA
// (arbitrates between the 2 resident blocks' phases — removing it cost 18%).
// NT stores keep Y out of L3 so X stays L3-resident across warm replays
// (wall ~= 0.7 x profiled with NT vs 0.9 without). Epilogue routes acc
// through LDS (aliased over dead As/Bs) and emits dense 16B NT stores
// (full 128B lines) — WRITE_SIZE exactly 150528 KB (ideal).
__global__ __launch_bounds__(256, 2)
void gemm_fused(const float* __restrict__ X, const u16* __restrict__ Bw,
                const float* __restrict__ bias, float* __restrict__ Y) {
    // XCD-aware bijective swizzle: 2352 blocks = 8 * 294
    const int b = blockIdx.x;
    const int bid = (b & 7) * 294 + (b >> 3);
    const int mt = bid / 6, nt = bid - mt * 6;
    const int m0 = mt * 128, n0 = nt * 128;

    const int tid = threadIdx.x;
    const int lane = tid & 63;
    const int w = tid >> 6;
    const int wm = w >> 1, wn = w & 1;

    // 64 KB pool: staging (As 2x16K | Bs 2x16K) in the K-loop,
    // then reused as a 128x128 f32 output tile in the epilogue.
    __shared__ __align__(16) float pool[16384];
    u16 (*As)[128 * 64] = (u16(*)[128 * 64])pool;
    u16 (*Bs)[128 * 64] = (u16(*)[128 * 64])((char*)pool + 32768);

    f32x4 acc[4][4];
    #pragma unroll
    for (int i = 0; i < 4; ++i)
        #pragma unroll
        for (int j = 0; j < 4; ++j)
            acc[i][j] = (f32x4){0.f, 0.f, 0.f, 0.f};

    const int arow = tid >> 4;      // 0..15
    const int agg  = tid & 15;      // 16B fp32 granule within row
    const int bg = lane & 7;

    float4 preA[8], preB[8];

    auto load_a = [&](float4 (&p)[8], int k0) {
        const float4* src = (const float4*)(X + (long)m0 * K_DIM + k0);
        #pragma unroll
        for (int i = 0; i < 8; ++i) {
            int r = arow + 16 * i;
            p[i] = src[(long)r * (K_DIM / 4) + agg];
        }
    };

    auto write_a = [&](int buf, const float4 (&p)[8]) {
        #pragma unroll
        for (int i = 0; i < 8; ++i) {
            int r = arow + 16 * i;
            int pb = (agg * 8) ^ ((r & 7) << 4);   // bf16 byte offset in row
            u16x4 hv;
            hv.x = f2bf(p[i].x);
            hv.y = f2bf(p[i].y);
            hv.z = f2bf(p[i].z);
            hv.w = f2bf(p[i].w);
            *(u16x4*)&As[buf][r * 64 + (pb >> 1)] = hv;
        }
    };

    auto stage_b = [&](int buf, int k0) {
        #pragma unroll
        for (int j = 0; j < 4; ++j) {
            int rowbase = j * 32 + w * 8;
            int row = rowbase + (lane >> 3);
            // pre-swizzled global source, linear LDS dest (base + lane*16)
            const char* src = (const char*)Bw + ((long)(n0 + row) * K_DIM + k0) * 2 +
                              ((bg * 16) ^ ((row & 7) << 4));
            gld_lds16(src, (void*)&Bs[buf][rowbase * 64]);
        }
    };

    auto compute = [&](int buf) {
        #pragma unroll
        for (int h = 0; h < 2; ++h) {
            bf16x8 av[4], bv_[4];
            #pragma unroll
            for (int mf = 0; mf < 4; ++mf) {
                int r = wm * 64 + mf * 16 + (lane & 15);
                int pb = (h * 64 + ((lane >> 4) << 4)) ^ ((r & 7) << 4);
                av[mf] = *(const bf16x8*)&As[buf][r * 64 + (pb >> 1)];
            }
            #pragma unroll
            for (int nf = 0; nf < 4; ++nf) {
                int r = wn * 64 + nf * 16 + (lane & 15);
                int pb = (h * 64 + ((lane >> 4) << 4)) ^ ((r & 7) << 4);
                bv_[nf] = *(const bf16x8*)&Bs[buf][r * 64 + (pb >> 1)];
            }
            __builtin_amdgcn_s_setprio(1);
            #pragma unroll
            for (int mf = 0; mf < 4; ++mf)
                #pragma unroll
                for (int nf = 0; nf < 4; ++nf)
                    acc[mf][nf] = __builtin_amdgcn_mfma_f32_16x16x32_bf16(
                        av[mf], bv_[nf], acc[mf][nf], 0, 0, 0);
            __builtin_amdgcn_s_setprio(0);
        }
    };

    // ---- prologue ----
    load_a(preA, 0);
    stage_b(0, 0);
    load_a(preB, 64);
    write_a(0, preA);          // waits only on preA loads; preB + gld_lds stay in flight
    __syncthreads();

    const int NT = K_DIM / 64;  // 12
    #pragma unroll 1
    for (int t2 = 0; t2 < NT; t2 += 2) {
        // ---- even iter t=t2: compute buf 0 ----
        if (t2 + 1 < NT) {
            write_a(1, preB);              // A for t+1 (regs drained by prev barrier)
            stage_b(1, (t2 + 1) * 64);     // B for t+1
        }
        if (t2 + 2 < NT) load_a(preA, (t2 + 2) * 64);  // A regs for t+2
        compute(0);
        __syncthreads();

        // ---- odd iter t=t2+1: compute buf 1 ----
        if (t2 + 2 < NT) {
            write_a(0, preA);
            stage_b(0, (t2 + 2) * 64);
        }
        if (t2 + 3 < NT) load_a(preB, (t2 + 3) * 64);
        compute(1);
        __syncthreads();
    }
    // final loop barrier already passed: As/Bs are dead, pool is free.

    // ---- epilogue stage 1: acc (+bias) -> LDS tile [128][128] f32 ----
    // C/D layout: col=lane&15, row=(lane>>4)*4+reg.
    // Bank swizzle: col' = col ^ (((row>>2)&1)<<4) -> 2-way conflicts only (free).
    const int colq = lane & 15;
    const int rowq = (lane >> 4) * 4;
    #pragma unroll
    for (int nf = 0; nf < 4; ++nf) {
        int col = wn * 64 + nf * 16 + colq;
        float bi = bias[n0 + col];
        #pragma unroll
        for (int mf = 0; mf < 4; ++mf) {
            int rbase = wm * 64 + mf * 16 + rowq;
            #pragma unroll
            for (int r = 0; r < 4; ++r) {
                int row = rbase + r;
                int colS = col ^ (((row >> 2) & 1) << 4);
                pool[row * 128 + colS] = acc[mf][nf][r] + bi;
            }
        }
    }
    __syncthreads();

    // ---- epilogue stage 2: dense 16B NT stores (full 128B lines) ----
    // 4096 float4 chunks; consecutive tids cover consecutive 16B within a row.
    #pragma unroll
    for (int i = 0; i < 16; ++i) {
        int chunk = i * 256 + tid;
        int row = chunk >> 5;          // 0..127
        int g = chunk & 31;            // float4 index within row
        int gs = g ^ (((row >> 2) & 1) << 2);
        f32x4 v = *(const f32x4*)&pool[row * 128 + gs * 4];
        __builtin_nontemporal_store(v,
            (f32x4*)&Y[(long)(m0 + row) * N_DIM + n0 + g * 4]);
    }
}

extern "C" void kernel_launch(void* const* d_in, const int* in_sizes, int n_in,
                              void* d_out, int out_size, void* d_ws, size_t ws_size,
                              hipStream_t stream) {
    const float* x      = (const float*)d_in[0];
    const float* qkv_w  = (const float*)d_in[1];
    const float* qkv_b  = (const float*)d_in[2];
    const float* proj_w = (const float*)d_in[3];
    const float* proj_b = (const float*)d_in[4];
    const float* pe     = (const float*)d_in[5];
    float* y = (float*)d_out;

    u16*   Bw   = (u16*)d_ws;
    float* bias = (float*)((char*)d_ws + (size_t)N_DIM * K_DIM * 2);

    fold_weights<<<768, 256, 0, stream>>>(qkv_w, qkv_b, proj_w, proj_b, pe, Bw, bias);
    gemm_fused<<<(M_DIM / 128) * (N_DIM / 128), 256, 0, stream>>>(x, Bw, bias, y);
}